// Round 10
// baseline (366.919 us; speedup 1.0000x reference)
//
#include <hip/hip_runtime.h>

typedef _Float16 f16x4 __attribute__((ext_vector_type(4)));
typedef _Float16 f16x8 __attribute__((ext_vector_type(8)));
typedef float    f32x16 __attribute__((ext_vector_type(16)));
typedef float    f32x4v __attribute__((ext_vector_type(4)));

// ---- ws byte offsets (total 8,486,912 B) ----
#define HN_OFF   0u                      // 8192 fp32: 0.5*||e||^2   (32 KB)
#define BEST_OFF 32768u                  // 8192 u64 packed best     (64 KB)
#define ERH_OFF  98304u                  // e-hi, A-FRAG-TILED       (2 MB)
#define ERL_OFF  (98304u + 2097152u)     // e-lo * 2^11, same layout
#define XRH_OFF  (98304u + 2u * 2097152u) // x-hi, row-major
#define XRL_OFF  (98304u + 3u * 2097152u) // x-lo * 2^11, row-major

// ---- out layout (float indices): [quantized NCHW 1M][encodings 64M] ----
#define OUT_Q    0
#define OUT_ENC  1048576

// e-plane DRAM layout = A-FRAG-TILED (identical to r8/r9; verified passing):
// f16 elem (code w, ch c): T=w>>6, cs=(w>>5)&1, col=w&31, s=c>>4, hf=(c>>3)&1
//   byte addr = T*16384 + cs*8192 + s*1024 + hf*512 + col*16 + (c&7)*2
// A wave's frag (ct, s) = 1 KB contiguous; lane l at +(l>>5)*512+(l&31)*16.

// K1: split x,e into f16 hi + scaled-lo planes; e-planes A-frag-tiled;
// fused 0.5*||e||^2; zero-init packed-best array. (unchanged, verified)
__global__ __launch_bounds__(256) void k1_convert(const float* __restrict__ x,
                                                  const float* __restrict__ e,
                                                  char* __restrict__ wsb) {
    int bx = blockIdx.x, tid = threadIdx.x;
    bool is_e = bx < 1024;
    const float* src = is_e ? e : x;
    int sec = is_e ? bx : bx - 1024;
    size_t off = (size_t)sec * 1024 + tid * 4;      // float-element offset
    float4 v = *(const float4*)(src + off);

    f16x4 hi, lo;
    hi[0] = (_Float16)v.x; hi[1] = (_Float16)v.y;
    hi[2] = (_Float16)v.z; hi[3] = (_Float16)v.w;
    lo[0] = (_Float16)((v.x - (float)hi[0]) * 2048.0f);
    lo[1] = (_Float16)((v.y - (float)hi[1]) * 2048.0f);
    lo[2] = (_Float16)((v.z - (float)hi[2]) * 2048.0f);
    lo[3] = (_Float16)((v.w - (float)hi[3]) * 2048.0f);

    if (is_e) {
        int code = (int)(off >> 7);                 // sec*8 + (tid>>5)
        int c = (tid & 31) * 4;                     // 4 consecutive channels
        int T = code >> 6, cs = (code >> 5) & 1, colc = code & 31;
        int s = c >> 4, hf = (c >> 3) & 1;
        size_t dst = (size_t)T * 8192 + cs * 4096 + s * 512 + hf * 256
                   + colc * 8 + (c & 7);
        *(f16x4*)((_Float16*)(wsb + ERH_OFF) + dst) = hi;
        *(f16x4*)((_Float16*)(wsb + ERL_OFF) + dst) = lo;

        float ss = v.x * v.x + v.y * v.y + v.z * v.z + v.w * v.w;
        for (int o = 16; o > 0; o >>= 1) ss += __shfl_down(ss, o, 32);
        if ((tid & 31) == 0)
            ((float*)(wsb + HN_OFF))[code] = 0.5f * ss;
    } else {
        _Float16* ph = (_Float16*)(wsb + XRH_OFF);
        _Float16* pl = (_Float16*)(wsb + XRL_OFF);
        *(f16x4*)(ph + off) = hi;
        *(f16x4*)(pl + off) = lo;
        if (sec < 32)
            ((unsigned long long*)(wsb + BEST_OFF))[sec * 256 + tid] = 0ull;
    }
}

// K2: heterogeneous grid, 1152 blocks x 256 thr.
//   bid 0..127   : fill blocks (FIRST in dispatch order): issue 2 MB each of
//                  enc-zero stores (256 MB total) and exit. No LDS, no
//                  barriers, tiny VGPR — they release wave slots in ~us and
//                  the write drain (41 us at HBM) runs on the WRITE path in
//                  the background while compute uses the READ path.
//   bid 128..1151: compute blocks (1024): zero-sync, zero-redundancy,
//                  operand-swapped direct-load MFMA argmax.
//                  Block = 64 rows; wave (rs=w&1, cs=w>>1): rows rs*32+col in
//                  regs (B-op), code-half cs (16 ct-groups, disjoint reads ->
//                  512 MB aggregate, L1-dedups the 2 rs-waves). 4096 waves =
//                  3 waves/SIMD resident (vs r9's 2) and NO sync anywhere:
//                  the CU scheduler can finally overlap load/MFMA/VALU
//                  chains across waves (r6-r9: every variant serialized).
__global__ __launch_bounds__(256, 3) void k2_mfma(char* __restrict__ wsb,
                                                  float* __restrict__ out) {
    int tid = threadIdx.x;
    int bid = blockIdx.x;

    if (bid < 128) {
        // ---- fill block: 2 MB enc-zero (512 f32x4/thread), then exit ----
        f32x4v z4 = {0.f, 0.f, 0.f, 0.f};
        f32x4v* dst = (f32x4v*)(out + OUT_ENC) + (size_t)bid * 131072 + tid;
        #pragma unroll 8
        for (int i = 0; i < 512; i++)
            dst[i * 256] = z4;
        return;
    }

    const _Float16* xrh = (const _Float16*)(wsb + XRH_OFF);
    const _Float16* xrl = (const _Float16*)(wsb + XRL_OFF);
    const float* hn = (const float*)(wsb + HN_OFF);
    unsigned long long* bestg = (unsigned long long*)(wsb + BEST_OFF);

    int m = bid - 128;
    int lane = tid & 63, wave = tid >> 6;
    int col = lane & 31, half = lane >> 5;
    int by = m & 7, g = m >> 3;              // XCD-pin: (128+m)%8 == m%8 == by
    int k0g = by * 1024;
    int rs = wave & 1, cs = wave >> 1;
    int row = g * 64 + rs * 32 + col;        // this lane's x-row (D col)

    // x-row fragments = MFMA B-operand, persistent registers (64 VGPR)
    f16x8 xh[8], xl[8];
    #pragma unroll
    for (int s = 0; s < 8; s++) {
        xh[s] = *(const f16x8*)(xrh + (size_t)row * 128 + s * 16 + half * 8);
        xl[s] = *(const f16x8*)(xrl + (size_t)row * 128 + s * 16 + half * 8);
    }

    // chunk base (bytes) in A-frag-tiled planes; per-lane frag offset
    size_t cbase = (size_t)by * 262144;      // by*16 tiles * 16384 B
    int laneoff = half * 512 + col * 16;
    const char* ph = (const char*)wsb + ERH_OFF + cbase + laneoff;
    const char* pl = (const char*)wsb + ERL_OFF + cbase + laneoff;

    float best = -3.0e38f;
    int bidx = 0;

    #pragma unroll 2
    for (int i = 0; i < 16; i++) {           // this wave's 16 code-groups
        int ct = cs * 16 + i;                // (T = ct>>1, cs_inner = ct&1)
        const char* bh = ph + (size_t)ct * 8192;
        const char* bl = pl + (size_t)ct * 8192;
        f32x16 a0, a1, a2;
        #pragma unroll
        for (int q = 0; q < 16; q++) { a0[q] = 0.f; a1[q] = 0.f; a2[q] = 0.f; }
        #pragma unroll
        for (int s = 0; s < 8; s++) {        // const offsets 0..7168
            f16x8 eh = *(const f16x8*)(bh + s * 1024);
            f16x8 el = *(const f16x8*)(bl + s * 1024);
            a0 = __builtin_amdgcn_mfma_f32_32x32x16_f16(eh, xh[s], a0, 0, 0, 0);
            a1 = __builtin_amdgcn_mfma_f32_32x32x16_f16(el, xh[s], a1, 0, 0, 0);
            a2 = __builtin_amdgcn_mfma_f32_32x32x16_f16(eh, xl[s], a2, 0, 0, 0);
        }
        // D: code = (r&3) + 8*(r>>2) + 4*half (ascending per lane), col = row.
        int cb = k0g + ct * 32 + 4 * half;
        #pragma unroll
        for (int gq = 0; gq < 4; gq++) {
            float4 h4 = *(const float4*)(hn + k0g + ct * 32 + gq * 8 + half * 4);
            #pragma unroll
            for (int j = 0; j < 4; j++) {
                int r = gq * 4 + j;
                float hv = (j == 0) ? h4.x : (j == 1) ? h4.y : (j == 2) ? h4.z : h4.w;
                float sc = a0[r] + (a1[r] + a2[r]) * (1.0f / 2048.0f) - hv;
                int cv = cb + gq * 8 + j;
                if (sc > best) { best = sc; bidx = cv; }  // > keeps first (min idx)
            }
        }
    }

    // merge lane <-> lane^32 (same row, disjoint code quarters), then atomic.
    // Waves (rs,0) and (rs,1) merge via the SAME atomicMax on bestg[row].
    {
        float qs = __shfl_xor(best, 32, 64);
        int qi = __shfl_xor(bidx, 32, 64);
        if (qs > best || (qs == best && qi < bidx)) { best = qs; bidx = qi; }
        if (half == 0) {
            unsigned ub = __float_as_uint(best);
            ub = ((int)ub < 0) ? ~ub : (ub | 0x80000000u);   // sortable map
            unsigned long long p = ((unsigned long long)ub << 32) |
                                   (unsigned long long)(0xFFFFFFFFu - (unsigned)bidx);
            atomicMax(&bestg[row], p);                        // tie -> min idx
        }
    }
}

// K3: decode packed best, write one-hot 1.0, gather e[bi] -> NCHW output.
// 128 blocks: 4-way channel split per n.
__global__ __launch_bounds__(256) void k3_final(const char* __restrict__ wsb,
                                                const float* __restrict__ wgt,
                                                float* __restrict__ out) {
    int bid = blockIdx.x;
    int n = (bid & 31) * 256 + threadIdx.x;   // 0..8191
    int q = bid >> 5;                          // channel quarter 0..3
    unsigned long long p = ((const unsigned long long*)(wsb + BEST_OFF))[n];
    int bi = (int)(0xFFFFFFFFu - (unsigned)(p & 0xFFFFFFFFull));

    if (q == 0)
        out[(size_t)OUT_ENC + (size_t)n * 8192 + bi] = 1.0f;

    // out0[((bq*128 + c)*32 + h)*32 + w], n = bq*1024 + h*32 + w
    int bq = n >> 10, hw = n & 1023;
    float* o = out + (size_t)bq * 131072 + hw + (size_t)q * 32 * 1024;
    const float4* wrow = (const float4*)(wgt + (size_t)bi * 128) + q * 8;
    #pragma unroll
    for (int c4 = 0; c4 < 8; c4++) {
        float4 v = wrow[c4];
        o[(c4 * 4 + 0) * 1024] = v.x;
        o[(c4 * 4 + 1) * 1024] = v.y;
        o[(c4 * 4 + 2) * 1024] = v.z;
        o[(c4 * 4 + 3) * 1024] = v.w;
    }
}

extern "C" void kernel_launch(void* const* d_in, const int* in_sizes, int n_in,
                              void* d_out, int out_size, void* d_ws, size_t ws_size,
                              hipStream_t stream) {
    const float* x = (const float*)d_in[0];   // [8,32,32,128] -> [8192][128]
    const float* e = (const float*)d_in[1];   // [8192][128]
    float* out = (float*)d_out;
    char* ws = (char*)d_ws;

    k1_convert<<<2048, 256, 0, stream>>>(x, e, ws);
    k2_mfma<<<1152, 256, 0, stream>>>(ws, out);
    k3_final<<<128, 256, 0, stream>>>(ws, e, out);
}